// Round 1
// baseline (61.841 us; speedup 1.0000x reference)
//
#include <hip/hip_runtime.h>
#include <hip/hip_bf16.h>
#include <cstdint>

#define B_ 16
#define T_ 4096
#define D_ 1024
#define E_ 64
#define THRESH 1.0f

#define MBLK 128      // timesteps per GEMM block
#define BK 64         // k-chunk
#define PAD_K 72      // padded LDS row length (bf16 elems): 144 B stride -> 2-way conflicts only

typedef float f32x4 __attribute__((ext_vector_type(4)));
typedef short s16x8 __attribute__((ext_vector_type(8)));

// fp32 -> bf16 hi/lo split: v = hi + lo + O(2^-17 * v)
// hi = truncate-to-bf16 (exact low-mantissa-zero fp32), r = v - hi exact, lo = trunc-bf16(r)
__device__ __forceinline__ void split1(float v, unsigned short& h, unsigned short& l) {
    unsigned u = __float_as_uint(v);
    float hf = __uint_as_float(u & 0xFFFF0000u);
    float r = v - hf;
    h = (unsigned short)(u >> 16);
    l = (unsigned short)(__float_as_uint(r) >> 16);
}

// ---------------- kernel 0: pre-split W into bf16 hi/lo ----------------
__global__ void wconv_kernel(const float* __restrict__ W,
                             unsigned short* __restrict__ Whi,
                             unsigned short* __restrict__ Wlo) {
    int i = (blockIdx.x * 256 + threadIdx.x) * 4;
    if (i >= E_ * D_) return;
    float4 v = *reinterpret_cast<const float4*>(W + i);
    ushort4 h, l;
    split1(v.x, h.x, l.x); split1(v.y, h.y, l.y);
    split1(v.z, h.z, l.z); split1(v.w, h.w, l.w);
    *reinterpret_cast<ushort4*>(Whi + i) = h;
    *reinterpret_cast<ushort4*>(Wlo + i) = l;
}

// ---------------- kernel 1: fused GEMM (hi/lo bf16 MFMA) + per-subchunk scan compose ----------------
// grid = 512 blocks (16 b * 32 chunks of 128 t), 256 threads (4 waves).
// Wave w owns t rows [w*32, w*32+32) of the block tile; composes its own (C,M).
__global__ __launch_bounds__(256, 2) void lif_gemm_kernel(
    const float* __restrict__ seq,
    const unsigned short* __restrict__ Whi, const unsigned short* __restrict__ Wlo,
    const float* __restrict__ bias, const float* __restrict__ beta_raw,
    float* __restrict__ Cw, float* __restrict__ Mw)
{
    __shared__ __align__(16) unsigned char lds[36864 + 18432];
    unsigned short* Ahi  = (unsigned short*)lds;                    // [128][72] bf16
    unsigned short* Alo  = (unsigned short*)(lds + 18432);          // [128][72]
    unsigned short* WhiL = (unsigned short*)(lds + 36864);          // [64][72]
    unsigned short* WloL = (unsigned short*)(lds + 36864 + 9216);   // [64][72]

    const int tid  = threadIdx.x;
    const int wave = tid >> 6;
    const int lane = tid & 63;
    const long row0 = (long)blockIdx.x * MBLK;

    f32x4 acc[2][4] = {};

    for (int k0 = 0; k0 < D_; k0 += BK) {
        __syncthreads();   // protect LDS against readers of previous chunk
        // ---- stage A: 128 rows x 64 k fp32 -> hi/lo bf16 in LDS ----
        #pragma unroll
        for (int i = 0; i < 8; ++i) {
            int linear = i * 256 + tid;        // 2048 float4 slots = 128*64 floats
            int r  = linear >> 4;              // row 0..127
            int kk = (linear & 15) << 2;       // k offset 0..60
            float4 v = *reinterpret_cast<const float4*>(seq + (row0 + r) * D_ + k0 + kk);
            ushort4 h, l;
            split1(v.x, h.x, l.x); split1(v.y, h.y, l.y);
            split1(v.z, h.z, l.z); split1(v.w, h.w, l.w);
            *reinterpret_cast<ushort4*>(Ahi + r * PAD_K + kk) = h;
            *reinterpret_cast<ushort4*>(Alo + r * PAD_K + kk) = l;
        }
        // ---- stage W chunk: 64 e x 64 k, hi/lo bf16 (pre-split, L2-hot) ----
        #pragma unroll
        for (int i = 0; i < 2; ++i) {
            int linear = i * 256 + tid;        // 512 slots of 8 ushort
            int r  = linear >> 3;              // e row 0..63
            int kk = (linear & 7) << 3;        // k offset 0..56
            uint4 vh = *reinterpret_cast<const uint4*>(Whi + r * D_ + k0 + kk);
            uint4 vl = *reinterpret_cast<const uint4*>(Wlo + r * D_ + k0 + kk);
            *reinterpret_cast<uint4*>(WhiL + r * PAD_K + kk) = vh;
            *reinterpret_cast<uint4*>(WloL + r * PAD_K + kk) = vl;
        }
        __syncthreads();
        // ---- MFMA: per wave, 2 m-tiles x 4 n-tiles, K-step 32 ----
        #pragma unroll
        for (int ks = 0; ks < BK; ks += 32) {
            const int kf = ks + ((lane >> 4) << 3);   // this lane's k base within chunk
            s16x8 ah[2], al[2], bh[4], bl[4];
            #pragma unroll
            for (int m = 0; m < 2; ++m) {
                int tr = wave * 32 + m * 16 + (lane & 15);
                ah[m] = *reinterpret_cast<const s16x8*>(Ahi + tr * PAD_K + kf);
                al[m] = *reinterpret_cast<const s16x8*>(Alo + tr * PAD_K + kf);
            }
            #pragma unroll
            for (int n = 0; n < 4; ++n) {
                int er = n * 16 + (lane & 15);
                bh[n] = *reinterpret_cast<const s16x8*>(WhiL + er * PAD_K + kf);
                bl[n] = *reinterpret_cast<const s16x8*>(WloL + er * PAD_K + kf);
            }
            // hi*hi, then lo*hi, then hi*lo (lo*lo dropped: ~2^-18 rel)
            #pragma unroll
            for (int m = 0; m < 2; ++m)
                #pragma unroll
                for (int n = 0; n < 4; ++n)
                    acc[m][n] = __builtin_amdgcn_mfma_f32_16x16x32_bf16(ah[m], bh[n], acc[m][n], 0, 0, 0);
            #pragma unroll
            for (int m = 0; m < 2; ++m)
                #pragma unroll
                for (int n = 0; n < 4; ++n)
                    acc[m][n] = __builtin_amdgcn_mfma_f32_16x16x32_bf16(al[m], bh[n], acc[m][n], 0, 0, 0);
            #pragma unroll
            for (int m = 0; m < 2; ++m)
                #pragma unroll
                for (int n = 0; n < 4; ++n)
                    acc[m][n] = __builtin_amdgcn_mfma_f32_16x16x32_bf16(ah[m], bl[n], acc[m][n], 0, 0, 0);
        }
    }
    __syncthreads();   // everyone done reading A/W LDS; now reuse as I-tile space

    // ---- write wave-private I tile [32 t][64 e] f32 (8 KB region per wave) ----
    float* Iw = (float*)(lds + wave * 8192);
    #pragma unroll
    for (int m = 0; m < 2; ++m)
        #pragma unroll
        for (int n = 0; n < 4; ++n) {
            int e  = n * 16 + (lane & 15);
            int tl = m * 16 + ((lane >> 4) << 2);   // C/D layout: col=lane&15, row=(lane>>4)*4+r
            #pragma unroll
            for (int r = 0; r < 4; ++r)
                Iw[(tl + r) * 64 + e] = acc[m][n][r];
        }
    // wave-private region: program order within wave suffices, no barrier

    // ---- serial compose over this wave's 32 timesteps: f(U)=min(beta*U + I_t, 1) ----
    // composed chunk form: U_out = min(A*U_in + C, M); A=beta^32 (recomputed in combine)
    const float be   = bias[lane];
    const float beta = 1.0f / (1.0f + __expf(-beta_raw[lane]));
    float Cc = 0.0f;
    float Mm = 3.0e38f;   // ~+inf identity; beta<1 so no overflow
    #pragma unroll
    for (int t = 0; t < 32; ++t) {
        float v = Iw[t * 64 + lane] + be;
        Cc = fmaf(beta, Cc, v);
        Mm = fminf(fmaf(beta, Mm, v), THRESH);
    }
    int sub = blockIdx.x * 4 + wave;   // global sub-chunk id = b*128 + local
    Cw[sub * 64 + lane] = Cc;
    Mw[sub * 64 + lane] = Mm;
}

// ---------------- kernel 2: combine 128 sub-chunks per batch + softmax ----------------
__global__ void lif_combine_kernel(const float* __restrict__ Cw, const float* __restrict__ Mw,
                                   const float* __restrict__ beta_raw, float* __restrict__ out)
{
    int b = blockIdx.x;
    int e = threadIdx.x;
    float beta = 1.0f / (1.0f + __expf(-beta_raw[e]));
    float A = beta * beta;  // beta^2
    A = A * A;              // ^4
    A = A * A;              // ^8
    A = A * A;              // ^16
    A = A * A;              // ^32
    float U = 0.0f;
    const float* Cp = Cw + (size_t)b * 128 * 64 + e;
    const float* Mp = Mw + (size_t)b * 128 * 64 + e;
    #pragma unroll 8
    for (int c = 0; c < 128; ++c)
        U = fminf(fmaf(A, U, Cp[c * 64]), Mp[c * 64]);
    // softmax across the 64 lanes (e dimension)
    float m = U;
    #pragma unroll
    for (int off = 32; off; off >>= 1) m = fmaxf(m, __shfl_xor(m, off, 64));
    float ex = __expf(U - m);
    float s = ex;
    #pragma unroll
    for (int off = 32; off; off >>= 1) s += __shfl_xor(s, off, 64);
    out[b * 64 + e] = ex / s;
}

extern "C" void kernel_launch(void* const* d_in, const int* in_sizes, int n_in,
                              void* d_out, int out_size, void* d_ws, size_t ws_size,
                              hipStream_t stream)
{
    const float* seq  = (const float*)d_in[0];
    const float* W    = (const float*)d_in[1];
    const float* bias = (const float*)d_in[2];
    const float* braw = (const float*)d_in[3];
    float* out = (float*)d_out;

    char* ws = (char*)d_ws;
    unsigned short* Whi = (unsigned short*)ws;                // 131072 B
    unsigned short* Wlo = (unsigned short*)(ws + 131072);     // 131072 B
    float* Cw = (float*)(ws + 262144);                        // 2048*64*4 = 524288 B
    float* Mw = (float*)(ws + 786432);                        // 524288 B; total 1.25 MB

    wconv_kernel<<<64, 256, 0, stream>>>(W, Whi, Wlo);
    lif_gemm_kernel<<<(B_ * T_) / MBLK, 256, 0, stream>>>(seq, Whi, Wlo, bias, braw, Cw, Mw);
    lif_combine_kernel<<<B_, E_, 0, stream>>>(Cw, Mw, braw, out);
}